// Round 2
// baseline (2626.511 us; speedup 1.0000x reference)
//
#include <hip/hip_runtime.h>
#include <cstdint>
#include <cstddef>

// APPNP: h0 = relu(x@W1+b1)@W2+b2 ; 10x { h = 0.9*A_hat h + 0.1*h0 } ; log_softmax
// N=100000, E=3200000, F=512, H=256, C=64
//
// Workspace budget note (R1 fix): keep total d_ws usage ~65 MB.
//   h0 (25.6M) + hA (25.6M) + srcs (12.8M) + dinv/counts/rowptr (~1.2M).
//   hB lives in d_out; per-edge weights are gathered from dinv[] on the fly.

#define BM 16

// ---------------- fused 2-layer MLP ----------------
__global__ __launch_bounds__(256) void mlp_kernel(
    const float* __restrict__ x, const float* __restrict__ W1,
    const float* __restrict__ b1, const float* __restrict__ W2,
    const float* __restrict__ b2, float* __restrict__ h0, int n)
{
    __shared__ float xs[BM][516];   // pad 512->516 (rows stay 16B aligned)
    __shared__ float hs[BM][260];   // pad 256->260
    const int tid = threadIdx.x;
    const int r0blk = blockIdx.x * BM;

    // load x tile (BM x 512), coalesced float4
    for (int i = tid; i < BM * 128; i += 256) {
        int r = i >> 7, c4 = i & 127;
        int rg = r0blk + r;
        float4 v = make_float4(0.f, 0.f, 0.f, 0.f);
        if (rg < n) v = *(const float4*)(x + (size_t)rg * 512 + c4 * 4);
        *(float4*)&xs[r][c4 * 4] = v;
    }
    __syncthreads();

    // phase 1: hmid = relu(x @ W1 + b1)   [BM x 256]
    {
        const int c0 = (tid >> 6) * 64 + (tid & 15) * 4; // 4 cols
        const int r0 = ((tid >> 4) & 3) * 4;             // 4 rows
        float4 bv = *(const float4*)&b1[c0];
        float4 acc[4] = {bv, bv, bv, bv};
        for (int k = 0; k < 512; k += 4) {
            float4 w0 = *(const float4*)&W1[(size_t)(k + 0) * 256 + c0];
            float4 w1 = *(const float4*)&W1[(size_t)(k + 1) * 256 + c0];
            float4 w2 = *(const float4*)&W1[(size_t)(k + 2) * 256 + c0];
            float4 w3 = *(const float4*)&W1[(size_t)(k + 3) * 256 + c0];
#pragma unroll
            for (int j = 0; j < 4; ++j) {
                float4 xv = *(const float4*)&xs[r0 + j][k];
                acc[j].x += xv.x * w0.x + xv.y * w1.x + xv.z * w2.x + xv.w * w3.x;
                acc[j].y += xv.x * w0.y + xv.y * w1.y + xv.z * w2.y + xv.w * w3.y;
                acc[j].z += xv.x * w0.z + xv.y * w1.z + xv.z * w2.z + xv.w * w3.z;
                acc[j].w += xv.x * w0.w + xv.y * w1.w + xv.z * w2.w + xv.w * w3.w;
            }
        }
#pragma unroll
        for (int j = 0; j < 4; ++j) {
            float4 v = acc[j];
            v.x = fmaxf(v.x, 0.f); v.y = fmaxf(v.y, 0.f);
            v.z = fmaxf(v.z, 0.f); v.w = fmaxf(v.w, 0.f);
            *(float4*)&hs[r0 + j][c0] = v;
        }
    }
    __syncthreads();

    // phase 2: h0 = hmid @ W2 + b2   [BM x 64]
    {
        const int c = tid & 63;
        const int rr = tid >> 6;     // rows rr, rr+4, rr+8, rr+12
        float bb = b2[c];
        float o[4] = {bb, bb, bb, bb};
        for (int k = 0; k < 256; k += 4) {
            float wk0 = W2[(size_t)(k + 0) * 64 + c];
            float wk1 = W2[(size_t)(k + 1) * 64 + c];
            float wk2 = W2[(size_t)(k + 2) * 64 + c];
            float wk3 = W2[(size_t)(k + 3) * 64 + c];
#pragma unroll
            for (int j = 0; j < 4; ++j) {
                float4 hv = *(const float4*)&hs[rr + j * 4][k];
                o[j] += hv.x * wk0 + hv.y * wk1 + hv.z * wk2 + hv.w * wk3;
            }
        }
#pragma unroll
        for (int j = 0; j < 4; ++j) {
            int rg = r0blk + rr + j * 4;
            if (rg < n) h0[(size_t)rg * 64 + c] = o[j];
        }
    }
}

// ---------------- graph preprocessing (CSR by dst) ----------------
__global__ void init_counts_kernel(int* __restrict__ counts, int n) {
    int i = blockIdx.x * blockDim.x + threadIdx.x;
    if (i < n) counts[i] = 1;   // self-loop
}

__global__ void count_kernel(const int* __restrict__ dstL, int* __restrict__ counts, int e) {
    int i = blockIdx.x * blockDim.x + threadIdx.x;
    int stride = gridDim.x * blockDim.x;
    for (; i < e; i += stride) atomicAdd(&counts[dstL[i]], 1);
}

__global__ void dinv_kernel(const int* __restrict__ counts, float* __restrict__ dinv, int n) {
    int i = blockIdx.x * blockDim.x + threadIdx.x;
    if (i < n) dinv[i] = 1.0f / sqrtf((float)counts[i]);   // deg >= 1 always (self-loop)
}

// exclusive scan of (counts[i]-1): A) per-block scan, B) scan of block sums, C) add offsets
__global__ __launch_bounds__(256) void scan_a(const int* __restrict__ counts,
                                              int* __restrict__ rowptr,
                                              int* __restrict__ bsums, int n)
{
    __shared__ int s[256];
    const int t = threadIdx.x;
    const int i = blockIdx.x * 256 + t;
    int v = (i < n) ? (counts[i] - 1) : 0;
    s[t] = v;
    __syncthreads();
    for (int off = 1; off < 256; off <<= 1) {
        int add = (t >= off) ? s[t - off] : 0;
        __syncthreads();
        s[t] += add;
        __syncthreads();
    }
    if (i < n) rowptr[i] = s[t] - v;       // exclusive, block-local
    if (t == 255) bsums[blockIdx.x] = s[255];
}

__global__ __launch_bounds__(512) void scan_b(const int* __restrict__ bsums,
                                              int* __restrict__ boff, int nb)
{
    __shared__ int s[512];
    const int t = threadIdx.x;
    int v = (t < nb) ? bsums[t] : 0;
    s[t] = v;
    __syncthreads();
    for (int off = 1; off < 512; off <<= 1) {
        int add = (t >= off) ? s[t - off] : 0;
        __syncthreads();
        s[t] += add;
        __syncthreads();
    }
    if (t < nb) boff[t] = s[t] - v;        // exclusive
}

__global__ __launch_bounds__(256) void scan_c(int* __restrict__ rowptr,
                                              int* __restrict__ cursor,
                                              const int* __restrict__ boff, int n, int e)
{
    int i = blockIdx.x * 256 + threadIdx.x;
    if (i < n) {
        int v = rowptr[i] + boff[blockIdx.x];
        rowptr[i] = v;
        cursor[i] = v;
    }
    if (i == 0) rowptr[n] = e;
}

__global__ void fill_kernel(const int* __restrict__ srcL, const int* __restrict__ dstL,
                            int* __restrict__ cursor, int* __restrict__ srcs, int e)
{
    int i = blockIdx.x * blockDim.x + threadIdx.x;
    int stride = gridDim.x * blockDim.x;
    for (; i < e; i += stride) {
        int s = srcL[i], d = dstL[i];
        int pos = atomicAdd(&cursor[d], 1);
        srcs[pos] = s;
    }
}

// ---------------- APPNP propagation step ----------------
// one wave per node, lane = feature (C=64).
// h_new[i] = 0.9*(dinv[i]*sum_e(dinv[src]*h[src]) + h[i]*dinv[i]^2) + 0.1*h0[i]
__global__ __launch_bounds__(256) void prop_kernel(
    const float* __restrict__ h, const float* __restrict__ h0f,
    float* __restrict__ hn, const int* __restrict__ rowptr,
    const int* __restrict__ srcs, const float* __restrict__ dinv, int n)
{
    const int wid = (blockIdx.x * blockDim.x + threadIdx.x) >> 6;
    const int lane = threadIdx.x & 63;
    if (wid >= n) return;
    const int e0 = rowptr[wid], e1 = rowptr[wid + 1];
    float acc = 0.f;
    int e = e0;
    for (; e + 3 < e1; e += 4) {
        int s0 = srcs[e], s1 = srcs[e + 1], s2 = srcs[e + 2], s3 = srcs[e + 3];
        float w0 = dinv[s0], w1 = dinv[s1], w2 = dinv[s2], w3 = dinv[s3];
        float v0 = h[(size_t)s0 * 64 + lane];
        float v1 = h[(size_t)s1 * 64 + lane];
        float v2 = h[(size_t)s2 * 64 + lane];
        float v3 = h[(size_t)s3 * 64 + lane];
        acc += w0 * v0;
        acc += w1 * v1;
        acc += w2 * v2;
        acc += w3 * v3;
    }
    for (; e < e1; ++e) {
        int s = srcs[e];
        acc += dinv[s] * h[(size_t)s * 64 + lane];
    }
    const float di = dinv[wid];
    const float hi = h[(size_t)wid * 64 + lane];
    hn[(size_t)wid * 64 + lane] =
        0.9f * (di * acc + hi * di * di) + 0.1f * h0f[(size_t)wid * 64 + lane];
}

// ---------------- log_softmax over C=64 (in-place safe) ----------------
__global__ __launch_bounds__(256) void logsoftmax_kernel(
    const float* __restrict__ h, float* __restrict__ out, int n)
{
    const int row = (blockIdx.x * blockDim.x + threadIdx.x) >> 6;
    const int lane = threadIdx.x & 63;
    if (row >= n) return;
    float v = h[(size_t)row * 64 + lane];
    float m = v;
#pragma unroll
    for (int o = 32; o > 0; o >>= 1) m = fmaxf(m, __shfl_xor(m, o));
    float ex = expf(v - m);
    float s = ex;
#pragma unroll
    for (int o = 32; o > 0; o >>= 1) s += __shfl_xor(s, o);
    out[(size_t)row * 64 + lane] = v - m - logf(s);
}

// ---------------- launcher ----------------
extern "C" void kernel_launch(void* const* d_in, const int* in_sizes, int n_in,
                              void* d_out, int out_size, void* d_ws, size_t ws_size,
                              hipStream_t stream)
{
    const float* x  = (const float*)d_in[0];
    const int*   ei = (const int*)d_in[1];
    const float* W1 = (const float*)d_in[2];
    const float* b1 = (const float*)d_in[3];
    const float* W2 = (const float*)d_in[4];
    const float* b2 = (const float*)d_in[5];
    float* out = (float*)d_out;

    const int n = in_sizes[0] / 512;    // 100000
    const int e = in_sizes[1] / 2;      // 3200000
    const int* srcL = ei;
    const int* dstL = ei + e;

    char* wsb = (char*)d_ws;
    size_t off = 0;
    auto alloc = [&](size_t bytes) -> void* {
        void* p = wsb + off;
        off = (off + bytes + 255) & ~(size_t)255;
        return p;
    };
    // lean layout: ~65 MB total
    float* h0   = (float*)alloc((size_t)n * 64 * 4);   // 25.6 MB
    float* hA   = (float*)alloc((size_t)n * 64 * 4);   // 25.6 MB
    int*   srcs = (int*)alloc((size_t)e * 4);          // 12.8 MB
    float* dinv = (float*)alloc((size_t)n * 4);        // 0.4 MB
    int*   counts = (int*)alloc((size_t)n * 4);        // 0.4 MB (reused as cursor)
    int*   rowptr = (int*)alloc((size_t)(n + 1) * 4);  // 0.4 MB
    int*   bsums  = (int*)alloc(4096);
    int*   boff   = (int*)alloc(4096);
    int*   cursor = counts;  // counts is dead after scan_a; alias

    const int nb = (n + 255) / 256;     // 391 (<512 required by scan_b)

    mlp_kernel<<<(n + BM - 1) / BM, 256, 0, stream>>>(x, W1, b1, W2, b2, h0, n);

    init_counts_kernel<<<nb, 256, 0, stream>>>(counts, n);
    count_kernel<<<2048, 256, 0, stream>>>(dstL, counts, e);
    dinv_kernel<<<nb, 256, 0, stream>>>(counts, dinv, n);
    scan_a<<<nb, 256, 0, stream>>>(counts, rowptr, bsums, n);
    scan_b<<<1, 512, 0, stream>>>(bsums, boff, nb);
    scan_c<<<nb, 256, 0, stream>>>(rowptr, cursor, boff, n, e);
    fill_kernel<<<2048, 256, 0, stream>>>(srcL, dstL, cursor, srcs, e);

    // ping-pong: h0 -> hA -> d_out -> hA -> ... iteration 9 (odd) lands in d_out
    const float* hcur = h0;
    float* bufs[2] = {hA, out};
    const int pgrid = (n * 64 + 255) / 256;
    for (int it = 0; it < 10; ++it) {
        float* hn = bufs[it & 1];
        prop_kernel<<<pgrid, 256, 0, stream>>>(hcur, h0, hn, rowptr, srcs, dinv, n);
        hcur = hn;
    }
    logsoftmax_kernel<<<pgrid, 256, 0, stream>>>(hcur, out, n);
}

// Round 3
// 1868.405 us; speedup vs baseline: 1.4058x; 1.4058x over previous
//
#include <hip/hip_runtime.h>
#include <cstdint>
#include <cstddef>

// APPNP: h0 = relu(x@W1+b1)@W2+b2 ; 10x { h = 0.9*A_hat h + 0.1*h0 } ; log_softmax
// N=100000, E=3200000, F=512, H=256, C=64
// R3: f16 MFMA MLP (W pre-transposed), f16 h storage in prop (half gather bytes).
// ws budget ~53 MB (R1 failed at ~104 MB; R2 passed at 65 MB — stay under).

typedef _Float16 half8 __attribute__((ext_vector_type(8)));
typedef float floatx4 __attribute__((ext_vector_type(4)));

__device__ inline float2 unpack2(uint u) {
    union { uint u; _Float16 h[2]; } c; c.u = u;
    return make_float2((float)c.h[0], (float)c.h[1]);
}
__device__ inline uint pack2(float a, float b) {
    union { uint u; _Float16 h[2]; } c; c.h[0] = (_Float16)a; c.h[1] = (_Float16)b;
    return c.u;
}

// ---------------- weight pre-transpose (fp32 -> f16, [k][c] -> [c][k]) ----------------
__global__ void transpose_w1(const float* __restrict__ W1, _Float16* __restrict__ W1t) {
    int i = blockIdx.x * 256 + threadIdx.x;          // over 512*256
    if (i < 512 * 256) {
        int k = i >> 8, c = i & 255;
        W1t[(size_t)c * 512 + k] = (_Float16)W1[i];
    }
}
__global__ void transpose_w2(const float* __restrict__ W2, _Float16* __restrict__ W2t) {
    int i = blockIdx.x * 256 + threadIdx.x;          // over 256*64
    if (i < 256 * 64) {
        int k = i >> 6, c = i & 63;
        W2t[(size_t)c * 256 + k] = (_Float16)W2[i];
    }
}

// ---------------- fused 2-layer MLP via f16 MFMA ----------------
// block = 256 thr = 4 waves; BM=32 rows/block (n=100000 -> 3125 blocks exactly).
// phase1: wave (wr=wid>>1, wc=wid&1): rows wr*16..+15, cols wc*128..+127 (8 col-tiles)
// phase2: wave wid: row-tile rt=wid>>1, col-tiles (wid&1)*2 + {0,1}
// frag maps (16x16x32): A[row=l&15][k=(l>>4)*8+j]; B[k=(l>>4)*8+j][col=l&15];
//                       D[row=(l>>4)*4+r][col=l&15]   (m89-verified)
__global__ __launch_bounds__(256) void mlp_kernel(
    const float* __restrict__ x, const _Float16* __restrict__ W1t,
    const float* __restrict__ b1, const _Float16* __restrict__ W2t,
    const float* __restrict__ b2, _Float16* __restrict__ h0h, int n)
{
    __shared__ __align__(16) _Float16 xs[32][520];        // 33.3 KB, 16B-aligned rows
    __shared__ __align__(16) _Float16 w1ts_raw[256 * 40]; // 20.5 KB; also hmid[32][264]
    _Float16 (*w1ts)[40]  = (_Float16(*)[40])w1ts_raw;
    _Float16 (*hmid)[264] = (_Float16(*)[264])w1ts_raw;

    const int tid  = threadIdx.x;
    const int lane = tid & 63;
    const int wid  = tid >> 6;
    const int r0blk = blockIdx.x * 32;
    const int lr = lane & 15;      // frag row/col index
    const int lg = lane >> 4;      // frag k-group

    // ---- load x tile 32x512 fp32 -> f16 LDS ----
    for (int fi = tid; fi < 32 * 128; fi += 256) {   // float4 index space
        int r = fi >> 7, k4 = (fi & 127) * 4;
        float4 v = *(const float4*)(x + (size_t)(r0blk + r) * 512 + k4);
        union { short4 s; _Float16 h[4]; } c;
        c.h[0] = (_Float16)v.x; c.h[1] = (_Float16)v.y;
        c.h[2] = (_Float16)v.z; c.h[3] = (_Float16)v.w;
        *(short4*)&xs[r][k4] = c.s;
    }

    // ---- phase 1: hmid = relu(x @ W1 + b1), rows 32 x cols 256 ----
    const int wr = wid >> 1, wc = wid & 1;
    floatx4 acc1[8];
#pragma unroll
    for (int ct = 0; ct < 8; ++ct) {
        float b = b1[wc * 128 + ct * 16 + lr];
        acc1[ct] = (floatx4){b, b, b, b};
    }

    for (int kk = 0; kk < 512; kk += 32) {
        __syncthreads();   // prev-step reads done (first iter: xs writes visible)
        // stage W1t tile: 256 cols x 32 k  (16 KB)
        for (int fi = tid; fi < 1024; fi += 256) {
            int c = fi >> 2, seg = (fi & 3) * 8;
            *(int4*)&w1ts[c][seg] = *(const int4*)&W1t[(size_t)c * 512 + kk + seg];
        }
        __syncthreads();
        half8 a = *(const half8*)&xs[wr * 16 + lr][kk + lg * 8];
#pragma unroll
        for (int ct = 0; ct < 8; ++ct) {
            half8 b = *(const half8*)&w1ts[wc * 128 + ct * 16 + lr][lg * 8];
            acc1[ct] = __builtin_amdgcn_mfma_f32_16x16x32_f16(a, b, acc1[ct], 0, 0, 0);
        }
    }

    __syncthreads();       // last mfma reads done; reuse region as hmid
#pragma unroll
    for (int ct = 0; ct < 8; ++ct) {
#pragma unroll
        for (int r = 0; r < 4; ++r) {
            float v = fmaxf(acc1[ct][r], 0.f);
            hmid[wr * 16 + lg * 4 + r][wc * 128 + ct * 16 + lr] = (_Float16)v;
        }
    }
    __syncthreads();

    // ---- phase 2: h0 = hmid @ W2 + b2, rows 32 x cols 64 ----
    const int rt = wid >> 1, ct2 = (wid & 1) * 2;
    floatx4 acc2[2] = {(floatx4){0,0,0,0}, (floatx4){0,0,0,0}};
    for (int kk = 0; kk < 256; kk += 32) {
        half8 a = *(const half8*)&hmid[rt * 16 + lr][kk + lg * 8];
#pragma unroll
        for (int q = 0; q < 2; ++q) {
            half8 b = *(const half8*)&W2t[(size_t)((ct2 + q) * 16 + lr) * 256 + kk + lg * 8];
            acc2[q] = __builtin_amdgcn_mfma_f32_16x16x32_f16(a, b, acc2[q], 0, 0, 0);
        }
    }
#pragma unroll
    for (int q = 0; q < 2; ++q) {
        int col = (ct2 + q) * 16 + lr;
        float bb = b2[col];
#pragma unroll
        for (int r = 0; r < 4; ++r) {
            int row = r0blk + rt * 16 + lg * 4 + r;
            h0h[(size_t)row * 64 + col] = (_Float16)(acc2[q][r] + bb);
        }
    }
}

// ---------------- graph preprocessing (CSR by dst) ----------------
__global__ void init_counts_kernel(int* __restrict__ counts, int n) {
    int i = blockIdx.x * blockDim.x + threadIdx.x;
    if (i < n) counts[i] = 1;   // self-loop
}

__global__ void count_kernel(const int* __restrict__ dstL, int* __restrict__ counts, int e) {
    int i = blockIdx.x * blockDim.x + threadIdx.x;
    int stride = gridDim.x * blockDim.x;
    for (; i < e; i += stride) atomicAdd(&counts[dstL[i]], 1);
}

__global__ void dinv_kernel(const int* __restrict__ counts, float* __restrict__ dinv, int n) {
    int i = blockIdx.x * blockDim.x + threadIdx.x;
    if (i < n) dinv[i] = 1.0f / sqrtf((float)counts[i]);   // deg >= 1 (self-loop)
}

__global__ __launch_bounds__(256) void scan_a(const int* __restrict__ counts,
                                              int* __restrict__ rowptr,
                                              int* __restrict__ bsums, int n)
{
    __shared__ int s[256];
    const int t = threadIdx.x;
    const int i = blockIdx.x * 256 + t;
    int v = (i < n) ? (counts[i] - 1) : 0;
    s[t] = v;
    __syncthreads();
    for (int off = 1; off < 256; off <<= 1) {
        int add = (t >= off) ? s[t - off] : 0;
        __syncthreads();
        s[t] += add;
        __syncthreads();
    }
    if (i < n) rowptr[i] = s[t] - v;
    if (t == 255) bsums[blockIdx.x] = s[255];
}

__global__ __launch_bounds__(512) void scan_b(const int* __restrict__ bsums,
                                              int* __restrict__ boff, int nb)
{
    __shared__ int s[512];
    const int t = threadIdx.x;
    int v = (t < nb) ? bsums[t] : 0;
    s[t] = v;
    __syncthreads();
    for (int off = 1; off < 512; off <<= 1) {
        int add = (t >= off) ? s[t - off] : 0;
        __syncthreads();
        s[t] += add;
        __syncthreads();
    }
    if (t < nb) boff[t] = s[t] - v;
}

__global__ __launch_bounds__(256) void scan_c(int* __restrict__ rowptr,
                                              int* __restrict__ cursor,
                                              const int* __restrict__ boff, int n, int e)
{
    int i = blockIdx.x * 256 + threadIdx.x;
    if (i < n) {
        int v = rowptr[i] + boff[blockIdx.x];
        rowptr[i] = v;
        cursor[i] = v;
    }
    if (i == 0) rowptr[n] = e;
}

__global__ void fill_kernel(const int* __restrict__ srcL, const int* __restrict__ dstL,
                            int* __restrict__ cursor, int* __restrict__ srcs, int e)
{
    int i = blockIdx.x * blockDim.x + threadIdx.x;
    int stride = gridDim.x * blockDim.x;
    for (; i < e; i += stride) {
        int s = srcL[i], d = dstL[i];
        int pos = atomicAdd(&cursor[d], 1);
        srcs[pos] = s;
    }
}

// ---------------- APPNP propagation step (f16 storage) ----------------
// one wave per dst node; lanes split: half_id = lane>>5 handles even/odd edges,
// lane&31 = feature-pair index (2 f16 per lane as packed uint).
__global__ __launch_bounds__(256) void prop_kernel(
    const uint* __restrict__ hu, const uint* __restrict__ h0u,
    uint* __restrict__ hnu, const int* __restrict__ rowptr,
    const int* __restrict__ srcs, const float* __restrict__ dinv, int n)
{
    const int wid = (blockIdx.x * blockDim.x + threadIdx.x) >> 6;
    const int lane = threadIdx.x & 63;
    if (wid >= n) return;
    const int half_id = lane >> 5;
    const int p = lane & 31;
    const int e0 = rowptr[wid], e1 = rowptr[wid + 1];
    float accx = 0.f, accy = 0.f;
    int e = e0 + half_id;
    for (; e + 2 < e1; e += 4) {            // 2 edges per half-wave per iter
        int s0 = srcs[e], s1 = srcs[e + 2];
        float w0 = dinv[s0], w1 = dinv[s1];
        uint v0 = hu[(size_t)s0 * 32 + p];
        uint v1 = hu[(size_t)s1 * 32 + p];
        float2 f0 = unpack2(v0), f1 = unpack2(v1);
        accx += w0 * f0.x; accy += w0 * f0.y;
        accx += w1 * f1.x; accy += w1 * f1.y;
    }
    if (e < e1) {
        int s = srcs[e];
        float w = dinv[s];
        float2 f = unpack2(hu[(size_t)s * 32 + p]);
        accx += w * f.x; accy += w * f.y;
    }
    // combine even/odd halves
    accx += __shfl_xor(accx, 32);
    accy += __shfl_xor(accy, 32);

    const float di = dinv[wid];
    float2 self = unpack2(hu[(size_t)wid * 32 + p]);
    float2 anc  = unpack2(h0u[(size_t)wid * 32 + p]);
    float ox = 0.9f * (di * accx + self.x * di * di) + 0.1f * anc.x;
    float oy = 0.9f * (di * accy + self.y * di * di) + 0.1f * anc.y;
    if (half_id == 0) hnu[(size_t)wid * 32 + p] = pack2(ox, oy);
}

// ---------------- log_softmax over C=64 (f16 in, fp32 out) ----------------
__global__ __launch_bounds__(256) void logsoftmax_kernel(
    const _Float16* __restrict__ h, float* __restrict__ out, int n)
{
    const int row = (blockIdx.x * blockDim.x + threadIdx.x) >> 6;
    const int lane = threadIdx.x & 63;
    if (row >= n) return;
    float v = (float)h[(size_t)row * 64 + lane];
    float m = v;
#pragma unroll
    for (int o = 32; o > 0; o >>= 1) m = fmaxf(m, __shfl_xor(m, o));
    float ex = expf(v - m);
    float s = ex;
#pragma unroll
    for (int o = 32; o > 0; o >>= 1) s += __shfl_xor(s, o);
    out[(size_t)row * 64 + lane] = v - m - logf(s);
}

// ---------------- launcher ----------------
extern "C" void kernel_launch(void* const* d_in, const int* in_sizes, int n_in,
                              void* d_out, int out_size, void* d_ws, size_t ws_size,
                              hipStream_t stream)
{
    const float* x  = (const float*)d_in[0];
    const int*   ei = (const int*)d_in[1];
    const float* W1 = (const float*)d_in[2];
    const float* b1 = (const float*)d_in[3];
    const float* W2 = (const float*)d_in[4];
    const float* b2 = (const float*)d_in[5];
    float* out = (float*)d_out;

    const int n = in_sizes[0] / 512;    // 100000
    const int e = in_sizes[1] / 2;      // 3200000
    const int* srcL = ei;
    const int* dstL = ei + e;

    char* wsb = (char*)d_ws;
    size_t off = 0;
    auto alloc = [&](size_t bytes) -> void* {
        void* p = wsb + off;
        off = (off + bytes + 255) & ~(size_t)255;
        return p;
    };
    // ~53 MB total
    _Float16* h0h = (_Float16*)alloc((size_t)n * 64 * 2);  // 12.8 MB
    _Float16* hp0 = (_Float16*)alloc((size_t)n * 64 * 2);  // 12.8 MB
    _Float16* hp1 = (_Float16*)alloc((size_t)n * 64 * 2);  // 12.8 MB
    int*   srcs   = (int*)alloc((size_t)e * 4);            // 12.8 MB
    float* dinv   = (float*)alloc((size_t)n * 4);
    int*   counts = (int*)alloc((size_t)n * 4);            // reused as cursor
    int*   rowptr = (int*)alloc((size_t)(n + 1) * 4);
    int*   bsums  = (int*)alloc(4096);
    int*   boff   = (int*)alloc(4096);
    _Float16* W1t = (_Float16*)alloc((size_t)512 * 256 * 2);
    _Float16* W2t = (_Float16*)alloc((size_t)256 * 64 * 2);
    int* cursor = counts;

    const int nb = (n + 255) / 256;     // 391 (< 512 for scan_b)

    transpose_w1<<<(512 * 256 + 255) / 256, 256, 0, stream>>>(W1, W1t);
    transpose_w2<<<(256 * 64 + 255) / 256, 256, 0, stream>>>(W2, W2t);

    mlp_kernel<<<n / 32, 256, 0, stream>>>(x, W1t, b1, W2t, b2, h0h, n);

    init_counts_kernel<<<nb, 256, 0, stream>>>(counts, n);
    count_kernel<<<2048, 256, 0, stream>>>(dstL, counts, e);
    dinv_kernel<<<nb, 256, 0, stream>>>(counts, dinv, n);
    scan_a<<<nb, 256, 0, stream>>>(counts, rowptr, bsums, n);
    scan_b<<<1, 512, 0, stream>>>(bsums, boff, nb);
    scan_c<<<nb, 256, 0, stream>>>(rowptr, cursor, boff, n, e);
    fill_kernel<<<2048, 256, 0, stream>>>(srcL, dstL, cursor, srcs, e);

    // ping-pong: h0h -> hp0 -> hp1 -> hp0 ... iter9 lands in hp1
    const int pgrid = (n * 64 + 255) / 256;
    const uint* hin = (const uint*)h0h;
    uint* bufs[2] = {(uint*)hp0, (uint*)hp1};
    for (int it = 0; it < 10; ++it) {
        uint* hn = bufs[it & 1];
        prop_kernel<<<pgrid, 256, 0, stream>>>(hin, (const uint*)h0h, hn,
                                               rowptr, srcs, dinv, n);
        hin = hn;
    }
    logsoftmax_kernel<<<pgrid, 256, 0, stream>>>((const _Float16*)hin, out, n);
}